// Round 3
// baseline (172.723 us; speedup 1.0000x reference)
//
#include <hip/hip_runtime.h>

// B=1024, S=512, M=64, K=64, V=128, E=64, NQ=10000, C=4.

// Workspace layout (float offsets)
#define WS_EQ     0          // eq[10001][64]  = exp(qsim)
#define WS_EB     640064     // eb[512][64]    = exp(bias)
#define WS_PACK   672832     // int packT[512][1024] = qid | resp<<16
#define WS_PAT    1197120    // partials [3][2][64][512]  (i, half, m, t)
#define WS_W1     1393728    // w1[512][64] = eb * tp
#define WS_RDEN   1426496    // rden[1024][512] = 1/softmax-denominator
#define WS_CONST  1950784    // du, dw, dc, sp
#define WS_P0     1950800    // [64]
#define WS_Z0     1950864    // [64]
// total 1950928 floats = 7.8 MB

__device__ __forceinline__ float wred_sum(float x) {
    x += __shfl_xor(x, 1);
    x += __shfl_xor(x, 2);
    x += __shfl_xor(x, 4);
    x += __shfl_xor(x, 8);
    x += __shfl_xor(x, 16);
    x += __shfl_xor(x, 32);
    return x;
}

__device__ __forceinline__ float softplusf(float x) {
    return fmaxf(x, 0.0f) + log1pf(__expf(-fabsf(x)));
}

// ---------------------------------------------------------------------------
// k_prep:
//   blocks [0,626):   eq[q,m] = exp((q_table[q]@q2k_w + q2k_b) . key_embeds[m])
//   blocks [626,658): eb[t,m] = exp(0.3*alpha + 0.2*diff_sim)
//   block 658:        scalar constants + P0/Z0
//   blocks [659,787): tile-transpose q_ids/responses -> packT[s][b]
// ---------------------------------------------------------------------------
__global__ __launch_bounds__(256) void k_prep(
    const int* __restrict__ q_ids, const int* __restrict__ responses,
    const float* __restrict__ q_table, const float* __restrict__ key_embeds,
    const float* __restrict__ q2k_w, const float* __restrict__ q2k_b,
    const float* __restrict__ alpha_mean, const float* __restrict__ alpha_log_var,
    const float* __restrict__ beta_base, const float* __restrict__ beta_offsets,
    const float* __restrict__ alpha_noise, const float* __restrict__ beta_noise,
    const float* __restrict__ qa_w, const float* __restrict__ qa_b,
    const float* __restrict__ qae_w, const float* __restrict__ qae_b,
    const float* __restrict__ pred_w,
    const float* __restrict__ th0, const float* __restrict__ lv0,
    float* __restrict__ ws)
{
    const int tid = threadIdx.x;
    const int bid = blockIdx.x;
    if (bid < 626) {
        __shared__ float sw[64 * 64];    // q2k_w [e][k]
        __shared__ float ske[64 * 65];   // key_embeds [m][k], padded stride
        for (int i = tid; i < 4096; i += 256) sw[i] = q2k_w[i];
        for (int i = tid; i < 4096; i += 256) ske[(i >> 6) * 65 + (i & 63)] = key_embeds[i];
        __syncthreads();
        const int wid = tid >> 6, lane = tid & 63;
        float* eq = ws + WS_EQ;
        for (int qq = 0; qq < 4; ++qq) {
            int q = bid * 16 + wid * 4 + qq;
            int qc = (q < 10001) ? q : 10000;
            float qe = q_table[qc * 64 + lane];      // lane = e
            float qk = q2k_b[lane];                  // lane = k
            #pragma unroll
            for (int e = 0; e < 64; ++e)
                qk = fmaf(__shfl(qe, e), sw[e * 64 + lane], qk);
            float sim = 0.0f;                        // lane = m
            #pragma unroll
            for (int k = 0; k < 64; ++k)
                sim = fmaf(__shfl(qk, k), ske[lane * 65 + k], sim);
            if (q < 10001) eq[q * 64 + lane] = __expf(sim);
        }
    } else if (bid < 658) {
        float* eb = ws + WS_EB;
        int base = (bid - 626) * 1024 + tid * 4;
        #pragma unroll
        for (int j = 0; j < 4; ++j) {
            int idx = base + j;
            int m = idx & 63;
            float sdev  = __expf(0.5f * alpha_log_var[m]);
            float alpha = __expf(fmaf(alpha_noise[idx], sdev, alpha_mean[m]));
            float bse   = fmaf(beta_noise[idx], 0.1f, beta_base[m]);
            float o0 = softplusf(beta_offsets[m * 3 + 0]);
            float o1 = softplusf(beta_offsets[m * 3 + 1]);
            float cmean = (o0 + (o0 + o1)) * (1.0f / 3.0f);
            float bm = bse + cmean;
            float diff = __expf(-0.5f * bm * bm);
            eb[idx] = __expf(fmaf(0.3f, alpha, 0.2f * diff));
        }
    } else if (bid == 658) {
        const int wid = tid >> 6, lane = tid & 63;
        if (wid == 0) {
            float qv = 0.0f;
            for (int v = 0; v < 128; ++v) qv = fmaf(qae_w[lane * 128 + v], pred_w[v], qv);
            float du  = wred_sum(qa_w[lane] * qv);
            float dw  = wred_sum(qa_w[64 + lane] * qv);
            float dc1 = wred_sum(qa_b[lane] * qv);
            float cb  = wred_sum(fmaf(qae_b[lane], pred_w[lane],
                                      qae_b[64 + lane] * pred_w[64 + lane]));
            float sp  = wred_sum(pred_w[lane] + pred_w[64 + lane]);
            if (lane == 0) {
                float* c = ws + WS_CONST;
                c[0] = du; c[1] = dw; c[2] = dc1 + cb; c[3] = sp;
            }
        } else if (wid == 1) {
            float z0 = 0.0f;   // lane = m
            for (int v = 0; v < 128; ++v) z0 = fmaf(th0[lane * 128 + v], pred_w[v], z0);
            ws[WS_Z0 + lane] = z0;
            ws[WS_P0 + lane] = __expf(-lv0[lane * 128]);
        }
    } else {
        // transpose + pack: packT[s][b] = qid | resp<<16
        int tb = bid - 659;            // 0..127
        int sb = tb & 7;               // s-tile (8)
        int bb = tb >> 3;              // b-tile (16)
        __shared__ int tile[64][65];
        #pragma unroll
        for (int j = 0; j < 16; ++j) {
            int row = (tid >> 6) * 16 + j;   // b-dim within tile
            int col = tid & 63;              // s-dim within tile
            int gi = (bb * 64 + row) * 512 + sb * 64 + col;
            tile[row][col] = q_ids[gi] | (responses[gi] << 16);
        }
        __syncthreads();
        int* packT = (int*)(ws + WS_PACK);
        #pragma unroll
        for (int j = 0; j < 16; ++j) {
            int row = (tid >> 6) * 16 + j;   // s-dim
            int col = tid & 63;              // b-dim
            packT[(sb * 64 + row) * 1024 + bb * 64 + col] = tile[col][row];
        }
    }
}

// ---------------------------------------------------------------------------
// k_reduce: grid (t, half). Wave lane layout (r,c)=4 rows x 16 lanes, float4
// per lane. Per iteration: quad-uniform packT load, 4 softmax rows, store
// rinv per row, accumulate A1=sum a, A2=sum a*pr, A3=sum a^2*y.
// ---------------------------------------------------------------------------
__global__ __launch_bounds__(512) void k_reduce(float* __restrict__ ws)
{
    const int bid = blockIdx.x;
    const int t = bid & 511, h = bid >> 9;
    const int tid = threadIdx.x;
    const int wid = tid >> 6, lane = tid & 63;
    const int r = lane >> 4, c = lane & 15;
    const float* eq = ws + WS_EQ;
    const int* packT = (const int*)(ws + WS_PACK);
    const float* cst = ws + WS_CONST;
    float* rden = ws + WS_RDEN;
    const float du = cst[0], dw = cst[1], dc = cst[2], sp = cst[3];

    float ae0, ae1, ae2, ae3;
    {
        float p;
        p = 0.01f;        ae0 = logf(p) - log1pf(-p);
        p = 0.33333334f;  ae1 = logf(p) - log1pf(-p);
        p = 0.6666667f;   ae2 = logf(p) - log1pf(-p);
        p = 0.99f;        ae3 = logf(p) - log1pf(-p);
    }

    const float4 ebv = *(const float4*)(ws + WS_EB + t * 64 + c * 4);
    const int bbase = h * 512 + wid * 64;

    float4 a1v = {0.f,0.f,0.f,0.f}, a2v = {0.f,0.f,0.f,0.f}, a3v = {0.f,0.f,0.f,0.f};
    #pragma unroll 4
    for (int i = 0; i < 16; ++i) {
        int b = bbase + i * 4 + r;
        int pk = packT[t * 1024 + b];            // quad-uniform (16B/wave/iter)
        int qid  = pk & 0xFFFF;
        int resp = pk >> 16;
        float rn = (float)resp * 0.33333334f;
        float ae = (resp == 0) ? ae0 : (resp == 1) ? ae1 : (resp == 2) ? ae2 : ae3;
        float pv = fmaf(fabsf(rn - 0.5f), 2.0f, 0.5f);
        float yv = fmaf(ae, sp, fmaf(rn, dw, fmaf((float)qid * 1e-4f, du, dc)));
        float4 eqv = *(const float4*)(eq + qid * 64 + c * 4);
        float4 e4;
        e4.x = eqv.x * ebv.x; e4.y = eqv.y * ebv.y;
        e4.z = eqv.z * ebv.z; e4.w = eqv.w * ebv.w;
        float s = (e4.x + e4.y) + (e4.z + e4.w);
        s += __shfl_xor(s, 1);
        s += __shfl_xor(s, 2);
        s += __shfl_xor(s, 4);
        s += __shfl_xor(s, 8);
        float rinv = __builtin_amdgcn_rcpf(s);
        if (c == 0) rden[b * 512 + t] = rinv;    // for k_pred
        float4 a4;
        a4.x = e4.x * rinv; a4.y = e4.y * rinv; a4.z = e4.z * rinv; a4.w = e4.w * rinv;
        a1v.x += a4.x; a1v.y += a4.y; a1v.z += a4.z; a1v.w += a4.w;
        a2v.x = fmaf(a4.x, pv, a2v.x); a2v.y = fmaf(a4.y, pv, a2v.y);
        a2v.z = fmaf(a4.z, pv, a2v.z); a2v.w = fmaf(a4.w, pv, a2v.w);
        a3v.x = fmaf(a4.x * a4.x, yv, a3v.x); a3v.y = fmaf(a4.y * a4.y, yv, a3v.y);
        a3v.z = fmaf(a4.z * a4.z, yv, a3v.z); a3v.w = fmaf(a4.w * a4.w, yv, a3v.w);
    }
    // combine the 4 r-groups (different b's, same m-range)
    #pragma unroll
    for (int d = 16; d <= 32; d <<= 1) {
        a1v.x += __shfl_xor(a1v.x, d); a1v.y += __shfl_xor(a1v.y, d);
        a1v.z += __shfl_xor(a1v.z, d); a1v.w += __shfl_xor(a1v.w, d);
        a2v.x += __shfl_xor(a2v.x, d); a2v.y += __shfl_xor(a2v.y, d);
        a2v.z += __shfl_xor(a2v.z, d); a2v.w += __shfl_xor(a2v.w, d);
        a3v.x += __shfl_xor(a3v.x, d); a3v.y += __shfl_xor(a3v.y, d);
        a3v.z += __shfl_xor(a3v.z, d); a3v.w += __shfl_xor(a3v.w, d);
    }

    __shared__ float red[8][3][64];
    if (lane < 16) {
        *(float4*)&red[wid][0][lane * 4] = a1v;
        *(float4*)&red[wid][1][lane * 4] = a2v;
        *(float4*)&red[wid][2][lane * 4] = a3v;
    }
    __syncthreads();
    if (wid == 0) {
        float A1 = 0.f, A2 = 0.f, A3 = 0.f;
        #pragma unroll
        for (int w = 0; w < 8; ++w) {
            A1 += red[w][0][lane]; A2 += red[w][1][lane]; A3 += red[w][2][lane];
        }
        float* pat = ws + WS_PAT;
        pat[(h * 64 + lane) * 512 + t]           = A1;
        pat[65536 + (h * 64 + lane) * 512 + t]   = A2;
        pat[131072 + (h * 64 + lane) * 512 + t]  = A3;
    }
}

// ---------------------------------------------------------------------------
// k_scan: block per m, 1 wave. Combine halves, form g/gz, exclusive prefix
// scan over t, write w1[t,m] = eb[t,m] * (Z_{t-1}/P_{t-1}).
// ---------------------------------------------------------------------------
__global__ __launch_bounds__(64) void k_scan(float* __restrict__ ws)
{
    const int m = blockIdx.x, lane = threadIdx.x;
    const float* pat = ws + WS_PAT;
    float A1[8], A2[8], A3[8];
    #pragma unroll
    for (int i = 0; i < 3; ++i) {
        const float* p0 = pat + i * 65536 + m * 512 + lane * 8;
        const float* p1 = p0 + 32768;
        float4 u0 = *(const float4*)p0, u1 = *(const float4*)(p0 + 4);
        float4 v0 = *(const float4*)p1, v1 = *(const float4*)(p1 + 4);
        float* A = (i == 0) ? A1 : (i == 1) ? A2 : A3;
        A[0] = u0.x + v0.x; A[1] = u0.y + v0.y; A[2] = u0.z + v0.z; A[3] = u0.w + v0.w;
        A[4] = u1.x + v1.x; A[5] = u1.y + v1.y; A[6] = u1.z + v1.z; A[7] = u1.w + v1.w;
    }
    float g[8], gz[8];
    #pragma unroll
    for (int j = 0; j < 8; ++j) {
        float denom = A1[j] + 1e-8f;
        float gg = (A2[j] / denom) * (A1[j] * (1.0f / 1024.0f));
        float zz = 0.5f * (A3[j] / denom);
        g[j] = gg; gz[j] = gg * zz;
    }
    float sg = 0.0f, sz = 0.0f;
    #pragma unroll
    for (int j = 0; j < 8; ++j) { sg += g[j]; sz += gz[j]; }
    #pragma unroll
    for (int d = 1; d < 64; d <<= 1) {
        float t1 = __shfl_up(sg, d);
        float t2 = __shfl_up(sz, d);
        if (lane >= d) { sg += t1; sz += t2; }
    }
    float eg = __shfl_up(sg, 1);
    float ez = __shfl_up(sz, 1);
    if (lane == 0) { eg = 0.0f; ez = 0.0f; }
    float P = ws[WS_P0 + m] + eg;
    float Z = ws[WS_Z0 + m] + ez;
    const float* eb = ws + WS_EB;
    float* w1 = ws + WS_W1;
    #pragma unroll
    for (int j = 0; j < 8; ++j) {
        int t = lane * 8 + j;
        w1[t * 64 + m] = (Z / P) * eb[t * 64 + m];
        Z += gz[j];
        P += g[j];
    }
}

// ---------------------------------------------------------------------------
// k_pred: block per b, wave lane layout (r,c). pred[b,t] =
//   (sum_m eq*w1) * rden[b,t] + pb.  4 t's per iteration.
// ---------------------------------------------------------------------------
__global__ __launch_bounds__(512) void k_pred(
    const int* __restrict__ q_ids, const float* __restrict__ pred_b,
    const float* __restrict__ ws, float* __restrict__ out)
{
    const int b = blockIdx.x;
    const int tid = threadIdx.x, wid = tid >> 6, lane = tid & 63;
    const int r = lane >> 4, c = lane & 15;
    const int t0 = wid * 64;
    const float* eq = ws + WS_EQ;
    const float* w1 = ws + WS_W1;
    const float* rden = ws + WS_RDEN;
    const float pb = pred_b[0];
    float keep = 0.0f;
    #pragma unroll 4
    for (int i = 0; i < 16; ++i) {
        int t = t0 + i * 4 + r;
        int qid = q_ids[b * 512 + t];            // quad-uniform (16B/wave/iter)
        float4 eqv = *(const float4*)(eq + qid * 64 + c * 4);
        float4 w1v = *(const float4*)(w1 + t * 64 + c * 4);
        float num = fmaf(eqv.w, w1v.w, fmaf(eqv.z, w1v.z, fmaf(eqv.y, w1v.y, eqv.x * w1v.x)));
        num += __shfl_xor(num, 1);
        num += __shfl_xor(num, 2);
        num += __shfl_xor(num, 4);
        num += __shfl_xor(num, 8);
        float v = __shfl(num, (lane & 3) * 16);
        if ((lane >> 2) == i) keep = v;
    }
    float rinv = rden[b * 512 + t0 + lane];      // coalesced
    out[b * 512 + t0 + lane] = fmaf(keep, rinv, pb);
}

// ---------------------------------------------------------------------------
extern "C" void kernel_launch(void* const* d_in, const int* in_sizes, int n_in,
                              void* d_out, int out_size, void* d_ws, size_t ws_size,
                              hipStream_t stream)
{
    (void)in_sizes; (void)n_in; (void)out_size; (void)ws_size;
    const int*   q_ids         = (const int*)d_in[0];
    const int*   responses     = (const int*)d_in[1];
    const float* q_table       = (const float*)d_in[2];
    const float* key_embeds    = (const float*)d_in[3];
    const float* alpha_mean    = (const float*)d_in[4];
    const float* alpha_log_var = (const float*)d_in[5];
    const float* beta_base     = (const float*)d_in[6];
    const float* beta_offsets  = (const float*)d_in[7];
    const float* th0           = (const float*)d_in[8];
    const float* lv0           = (const float*)d_in[9];
    const float* q2k_w         = (const float*)d_in[10];
    const float* q2k_b         = (const float*)d_in[11];
    const float* qa_w          = (const float*)d_in[12];
    const float* qa_b          = (const float*)d_in[13];
    const float* qae_w         = (const float*)d_in[14];
    const float* qae_b         = (const float*)d_in[15];
    const float* pred_w        = (const float*)d_in[16];
    const float* pred_bs       = (const float*)d_in[17];
    const float* alpha_noise   = (const float*)d_in[18];
    const float* beta_noise    = (const float*)d_in[19];
    float* ws  = (float*)d_ws;
    float* out = (float*)d_out;

    k_prep<<<dim3(787), dim3(256), 0, stream>>>(
        q_ids, responses, q_table, key_embeds, q2k_w, q2k_b,
        alpha_mean, alpha_log_var, beta_base, beta_offsets,
        alpha_noise, beta_noise, qa_w, qa_b, qae_w, qae_b,
        pred_w, th0, lv0, ws);
    k_reduce<<<dim3(1024), dim3(512), 0, stream>>>(ws);
    k_scan<<<dim3(64), dim3(64), 0, stream>>>(ws);
    k_pred<<<dim3(1024), dim3(512), 0, stream>>>(q_ids, pred_bs, ws, out);
}

// Round 4
// 151.110 us; speedup vs baseline: 1.1430x; 1.1430x over previous
//
#include <hip/hip_runtime.h>

// B=1024, S=512, M=64, K=64, V=128, E=64, NQ=10000, C=4.

// Workspace layout (float offsets)
#define WS_EQ     0          // eq[10001][64]  = exp(qsim)
#define WS_EB     640064     // eb[512][64]    = exp(bias)
#define WS_PACK   672832     // int packT[512][1024] = qid | resp<<16
#define WS_PAT    1197120    // partials [3][2][64][512]  (i, half, m, t)
#define WS_W1     1393728    // w1[512][64] = eb * tp
#define WS_RDEN   1426496    // rden[1024][512] = 1/softmax-denominator
#define WS_CONST  1950784    // du, dw, dc, sp
#define WS_P0     1950800    // [64]
#define WS_Z0     1950864    // [64]
#define WS_W2T    1950928    // W2T[m][e] = sum_k q2k_w[e,k]*ke[m,k]
#define WS_C0     1955024    // c0[m] = sum_k q2k_b[k]*ke[m,k]
// total 1955088 floats = 7.82 MB

__device__ __forceinline__ float wred_sum(float x) {
    x += __shfl_xor(x, 1);
    x += __shfl_xor(x, 2);
    x += __shfl_xor(x, 4);
    x += __shfl_xor(x, 8);
    x += __shfl_xor(x, 16);
    x += __shfl_xor(x, 32);
    return x;
}

__device__ __forceinline__ float softplusf(float x) {
    return fmaxf(x, 0.0f) + log1pf(__expf(-fabsf(x)));
}

// ---------------------------------------------------------------------------
// k_pre0 (165 blocks):
//   blocks 0..3:    W2T[m][e] = sum_k q2k_w[e,k] * ke[m,k]
//   block  4:       scalar constants, P0/Z0, c0[m]
//   blocks 5..36:   eb[t,m] = exp(0.3*alpha + 0.2*diff_sim)
//   blocks 37..164: tile-transpose q_ids/responses -> packT[s][b]
// ---------------------------------------------------------------------------
__global__ __launch_bounds__(256) void k_pre0(
    const int* __restrict__ q_ids, const int* __restrict__ responses,
    const float* __restrict__ key_embeds,
    const float* __restrict__ q2k_w, const float* __restrict__ q2k_b,
    const float* __restrict__ alpha_mean, const float* __restrict__ alpha_log_var,
    const float* __restrict__ beta_base, const float* __restrict__ beta_offsets,
    const float* __restrict__ alpha_noise, const float* __restrict__ beta_noise,
    const float* __restrict__ qa_w, const float* __restrict__ qa_b,
    const float* __restrict__ qae_w, const float* __restrict__ qae_b,
    const float* __restrict__ pred_w,
    const float* __restrict__ th0, const float* __restrict__ lv0,
    float* __restrict__ ws)
{
    const int tid = threadIdx.x;
    const int bid = blockIdx.x;
    if (bid < 4) {
        // W2T: thread (esub-wave, m). e uniform per wave per jj -> scalar w-row loads.
        const int m = tid & 63;
        const int esub = __builtin_amdgcn_readfirstlane(tid >> 6);
        float kerow[64];
        #pragma unroll
        for (int j = 0; j < 16; ++j)
            *(float4*)&kerow[j * 4] = *(const float4*)(key_embeds + m * 64 + j * 4);
        float* w2t = ws + WS_W2T;
        #pragma unroll
        for (int jj = 0; jj < 4; ++jj) {
            int e = bid * 16 + esub * 4 + jj;
            const float* wrow = q2k_w + e * 64;   // uniform
            float acc = 0.0f;
            #pragma unroll
            for (int k = 0; k < 64; ++k) acc = fmaf(wrow[k], kerow[k], acc);
            w2t[m * 64 + e] = acc;
        }
    } else if (bid == 4) {
        const int wid = __builtin_amdgcn_readfirstlane(tid >> 6);
        const int lane = tid & 63;
        if (wid == 0) {
            float qv = 0.0f;
            for (int v = 0; v < 128; ++v) qv = fmaf(qae_w[lane * 128 + v], pred_w[v], qv);
            float du  = wred_sum(qa_w[lane] * qv);
            float dw  = wred_sum(qa_w[64 + lane] * qv);
            float dc1 = wred_sum(qa_b[lane] * qv);
            float cb  = wred_sum(fmaf(qae_b[lane], pred_w[lane],
                                      qae_b[64 + lane] * pred_w[64 + lane]));
            float sp  = wred_sum(pred_w[lane] + pred_w[64 + lane]);
            if (lane == 0) {
                float* c = ws + WS_CONST;
                c[0] = du; c[1] = dw; c[2] = dc1 + cb; c[3] = sp;
            }
        } else if (wid == 1) {
            float z0 = 0.0f;   // lane = m
            for (int v = 0; v < 128; ++v) z0 = fmaf(th0[lane * 128 + v], pred_w[v], z0);
            ws[WS_Z0 + lane] = z0;
            ws[WS_P0 + lane] = __expf(-lv0[lane * 128]);
        } else if (wid == 2) {
            // c0[m] = sum_k q2k_b[k] * ke[m,k]
            float acc = 0.0f;
            #pragma unroll
            for (int k = 0; k < 64; ++k) acc = fmaf(q2k_b[k], key_embeds[lane * 64 + k], acc);
            ws[WS_C0 + lane] = acc;
        }
    } else if (bid < 37) {
        float* eb = ws + WS_EB;
        int base = (bid - 5) * 1024 + tid * 4;
        #pragma unroll
        for (int j = 0; j < 4; ++j) {
            int idx = base + j;
            int m = idx & 63;
            float sdev  = __expf(0.5f * alpha_log_var[m]);
            float alpha = __expf(fmaf(alpha_noise[idx], sdev, alpha_mean[m]));
            float bse   = fmaf(beta_noise[idx], 0.1f, beta_base[m]);
            float o0 = softplusf(beta_offsets[m * 3 + 0]);
            float o1 = softplusf(beta_offsets[m * 3 + 1]);
            float cmean = (o0 + (o0 + o1)) * (1.0f / 3.0f);
            float bm = bse + cmean;
            float diff = __expf(-0.5f * bm * bm);
            eb[idx] = __expf(fmaf(0.3f, alpha, 0.2f * diff));
        }
    } else {
        // transpose + pack: packT[s][b] = qid | resp<<16
        int tb = bid - 37;             // 0..127
        int sb = tb & 7;               // s-tile (8)
        int bb = tb >> 3;              // b-tile (16)
        __shared__ int tile[64][65];
        #pragma unroll
        for (int j = 0; j < 16; ++j) {
            int row = (tid >> 6) * 16 + j;   // b-dim within tile
            int col = tid & 63;              // s-dim within tile
            int gi = (bb * 64 + row) * 512 + sb * 64 + col;
            tile[row][col] = q_ids[gi] | (responses[gi] << 16);
        }
        __syncthreads();
        int* packT = (int*)(ws + WS_PACK);
        #pragma unroll
        for (int j = 0; j < 16; ++j) {
            int row = (tid >> 6) * 16 + j;   // s-dim
            int col = tid & 63;              // b-dim
            packT[(sb * 64 + row) * 1024 + bb * 64 + col] = tile[col][row];
        }
    }
}

// ---------------------------------------------------------------------------
// k_prep: eq[q,m] = exp(c0[m] + sum_e qt[q,e] * W2T[m,e]).
// W2T row in 64 VGPRs/lane; qt row via wave-uniform scalar loads. Zero DS ops.
// ---------------------------------------------------------------------------
__global__ __launch_bounds__(256) void k_prep(
    const float* __restrict__ q_table, float* __restrict__ ws)
{
    const int tid = threadIdx.x;
    const int bid = blockIdx.x;
    const int wid = __builtin_amdgcn_readfirstlane(tid >> 6);
    const int lane = tid & 63;
    float w2row[64];
    const float* w2t = ws + WS_W2T + lane * 64;
    #pragma unroll
    for (int j = 0; j < 16; ++j)
        *(float4*)&w2row[j * 4] = *(const float4*)(w2t + j * 4);
    const float c0 = ws[WS_C0 + lane];
    float* eq = ws + WS_EQ;
    #pragma unroll
    for (int qq = 0; qq < 4; ++qq) {
        int q = bid * 16 + wid * 4 + qq;          // wave-uniform
        int qc = (q < 10001) ? q : 10000;
        const float* qrow = q_table + qc * 64;    // uniform -> s_load
        float sim = c0;
        #pragma unroll
        for (int e = 0; e < 64; ++e)
            sim = fmaf(qrow[e], w2row[e], sim);
        if (q < 10001) eq[q * 64 + lane] = __expf(sim);
    }
}

// ---------------------------------------------------------------------------
// k_reduce: grid (t, half). Wave lane layout (r,c)=4 rows x 16 lanes, float4
// per lane. Per iteration: quad-uniform packT load, 4 softmax rows, store
// rinv per row, accumulate A1=sum a, A2=sum a*pr, A3=sum a^2*y.
// ---------------------------------------------------------------------------
__global__ __launch_bounds__(512) void k_reduce(float* __restrict__ ws)
{
    const int bid = blockIdx.x;
    const int t = bid & 511, h = bid >> 9;
    const int tid = threadIdx.x;
    const int wid = tid >> 6, lane = tid & 63;
    const int r = lane >> 4, c = lane & 15;
    const float* eq = ws + WS_EQ;
    const int* packT = (const int*)(ws + WS_PACK);
    const float* cst = ws + WS_CONST;
    float* rden = ws + WS_RDEN;
    const float du = cst[0], dw = cst[1], dc = cst[2], sp = cst[3];

    float ae0, ae1, ae2, ae3;
    {
        float p;
        p = 0.01f;        ae0 = logf(p) - log1pf(-p);
        p = 0.33333334f;  ae1 = logf(p) - log1pf(-p);
        p = 0.6666667f;   ae2 = logf(p) - log1pf(-p);
        p = 0.99f;        ae3 = logf(p) - log1pf(-p);
    }

    const float4 ebv = *(const float4*)(ws + WS_EB + t * 64 + c * 4);
    const int bbase = h * 512 + wid * 64;

    float4 a1v = {0.f,0.f,0.f,0.f}, a2v = {0.f,0.f,0.f,0.f}, a3v = {0.f,0.f,0.f,0.f};
    #pragma unroll 4
    for (int i = 0; i < 16; ++i) {
        int b = bbase + i * 4 + r;
        int pk = packT[t * 1024 + b];            // quad-uniform (16B/wave/iter)
        int qid  = pk & 0xFFFF;
        int resp = pk >> 16;
        float rn = (float)resp * 0.33333334f;
        float ae = (resp == 0) ? ae0 : (resp == 1) ? ae1 : (resp == 2) ? ae2 : ae3;
        float pv = fmaf(fabsf(rn - 0.5f), 2.0f, 0.5f);
        float yv = fmaf(ae, sp, fmaf(rn, dw, fmaf((float)qid * 1e-4f, du, dc)));
        float4 eqv = *(const float4*)(eq + qid * 64 + c * 4);
        float4 e4;
        e4.x = eqv.x * ebv.x; e4.y = eqv.y * ebv.y;
        e4.z = eqv.z * ebv.z; e4.w = eqv.w * ebv.w;
        float s = (e4.x + e4.y) + (e4.z + e4.w);
        s += __shfl_xor(s, 1);
        s += __shfl_xor(s, 2);
        s += __shfl_xor(s, 4);
        s += __shfl_xor(s, 8);
        float rinv = __builtin_amdgcn_rcpf(s);
        if (c == 0) rden[b * 512 + t] = rinv;    // for k_pred
        float4 a4;
        a4.x = e4.x * rinv; a4.y = e4.y * rinv; a4.z = e4.z * rinv; a4.w = e4.w * rinv;
        a1v.x += a4.x; a1v.y += a4.y; a1v.z += a4.z; a1v.w += a4.w;
        a2v.x = fmaf(a4.x, pv, a2v.x); a2v.y = fmaf(a4.y, pv, a2v.y);
        a2v.z = fmaf(a4.z, pv, a2v.z); a2v.w = fmaf(a4.w, pv, a2v.w);
        a3v.x = fmaf(a4.x * a4.x, yv, a3v.x); a3v.y = fmaf(a4.y * a4.y, yv, a3v.y);
        a3v.z = fmaf(a4.z * a4.z, yv, a3v.z); a3v.w = fmaf(a4.w * a4.w, yv, a3v.w);
    }
    // combine the 4 r-groups (different b's, same m-range)
    #pragma unroll
    for (int d = 16; d <= 32; d <<= 1) {
        a1v.x += __shfl_xor(a1v.x, d); a1v.y += __shfl_xor(a1v.y, d);
        a1v.z += __shfl_xor(a1v.z, d); a1v.w += __shfl_xor(a1v.w, d);
        a2v.x += __shfl_xor(a2v.x, d); a2v.y += __shfl_xor(a2v.y, d);
        a2v.z += __shfl_xor(a2v.z, d); a2v.w += __shfl_xor(a2v.w, d);
        a3v.x += __shfl_xor(a3v.x, d); a3v.y += __shfl_xor(a3v.y, d);
        a3v.z += __shfl_xor(a3v.z, d); a3v.w += __shfl_xor(a3v.w, d);
    }

    __shared__ float red[8][3][64];
    if (lane < 16) {
        *(float4*)&red[wid][0][lane * 4] = a1v;
        *(float4*)&red[wid][1][lane * 4] = a2v;
        *(float4*)&red[wid][2][lane * 4] = a3v;
    }
    __syncthreads();
    if (wid == 0) {
        float A1 = 0.f, A2 = 0.f, A3 = 0.f;
        #pragma unroll
        for (int w = 0; w < 8; ++w) {
            A1 += red[w][0][lane]; A2 += red[w][1][lane]; A3 += red[w][2][lane];
        }
        float* pat = ws + WS_PAT;
        pat[(h * 64 + lane) * 512 + t]           = A1;
        pat[65536 + (h * 64 + lane) * 512 + t]   = A2;
        pat[131072 + (h * 64 + lane) * 512 + t]  = A3;
    }
}

// ---------------------------------------------------------------------------
// k_scan: block per m, 1 wave. Combine halves, form g/gz, exclusive prefix
// scan over t, write w1[t,m] = eb[t,m] * (Z_{t-1}/P_{t-1}).
// ---------------------------------------------------------------------------
__global__ __launch_bounds__(64) void k_scan(float* __restrict__ ws)
{
    const int m = blockIdx.x, lane = threadIdx.x;
    const float* pat = ws + WS_PAT;
    float A1[8], A2[8], A3[8];
    #pragma unroll
    for (int i = 0; i < 3; ++i) {
        const float* p0 = pat + i * 65536 + m * 512 + lane * 8;
        const float* p1 = p0 + 32768;
        float4 u0 = *(const float4*)p0, u1 = *(const float4*)(p0 + 4);
        float4 v0 = *(const float4*)p1, v1 = *(const float4*)(p1 + 4);
        float* A = (i == 0) ? A1 : (i == 1) ? A2 : A3;
        A[0] = u0.x + v0.x; A[1] = u0.y + v0.y; A[2] = u0.z + v0.z; A[3] = u0.w + v0.w;
        A[4] = u1.x + v1.x; A[5] = u1.y + v1.y; A[6] = u1.z + v1.z; A[7] = u1.w + v1.w;
    }
    float g[8], gz[8];
    #pragma unroll
    for (int j = 0; j < 8; ++j) {
        float denom = A1[j] + 1e-8f;
        float gg = (A2[j] / denom) * (A1[j] * (1.0f / 1024.0f));
        float zz = 0.5f * (A3[j] / denom);
        g[j] = gg; gz[j] = gg * zz;
    }
    float sg = 0.0f, sz = 0.0f;
    #pragma unroll
    for (int j = 0; j < 8; ++j) { sg += g[j]; sz += gz[j]; }
    #pragma unroll
    for (int d = 1; d < 64; d <<= 1) {
        float t1 = __shfl_up(sg, d);
        float t2 = __shfl_up(sz, d);
        if (lane >= d) { sg += t1; sz += t2; }
    }
    float eg = __shfl_up(sg, 1);
    float ez = __shfl_up(sz, 1);
    if (lane == 0) { eg = 0.0f; ez = 0.0f; }
    float P = ws[WS_P0 + m] + eg;
    float Z = ws[WS_Z0 + m] + ez;
    const float* eb = ws + WS_EB;
    float* w1 = ws + WS_W1;
    #pragma unroll
    for (int j = 0; j < 8; ++j) {
        int t = lane * 8 + j;
        w1[t * 64 + m] = (Z / P) * eb[t * 64 + m];
        Z += gz[j];
        P += g[j];
    }
}

// ---------------------------------------------------------------------------
// k_pred: block per b, wave lane layout (r,c). 16 per-lane accumulators,
// zero in-loop DS; LDS transpose epilogue. pred[b,t] = num * rden + pb.
// ---------------------------------------------------------------------------
__global__ __launch_bounds__(512) void k_pred(
    const int* __restrict__ q_ids, const float* __restrict__ pred_b,
    const float* __restrict__ ws, float* __restrict__ out)
{
    const int b = blockIdx.x;
    const int tid = threadIdx.x, wid = tid >> 6, lane = tid & 63;
    const int r = lane >> 4, c = lane & 15;
    const int t0 = wid * 64;
    const float* eq = ws + WS_EQ;
    const float* w1 = ws + WS_W1;
    const float* rden = ws + WS_RDEN;
    const float pb = pred_b[0];
    float acc[16];
    #pragma unroll 4
    for (int i = 0; i < 16; ++i) {
        int t = t0 + i * 4 + r;
        int qid = q_ids[b * 512 + t];            // quad-uniform, 1 line/iter
        float4 eqv = *(const float4*)(eq + qid * 64 + c * 4);
        float4 w1v = *(const float4*)(w1 + t * 64 + c * 4);
        acc[i] = fmaf(eqv.w, w1v.w, fmaf(eqv.z, w1v.z, fmaf(eqv.y, w1v.y, eqv.x * w1v.x)));
    }
    // per-wave LDS transpose: part[tloc][c], stride 20 floats (16B-aligned rows)
    __shared__ float part[8 * 64 * 20];
    float* p = part + wid * 64 * 20;
    #pragma unroll
    for (int i = 0; i < 16; ++i)
        p[(i * 4 + r) * 20 + c] = acc[i];
    // same-wave LDS ops are in-order; no barrier needed
    float4 s0 = *(const float4*)(p + lane * 20);
    float4 s1 = *(const float4*)(p + lane * 20 + 4);
    float4 s2 = *(const float4*)(p + lane * 20 + 8);
    float4 s3 = *(const float4*)(p + lane * 20 + 12);
    float num = ((s0.x + s0.y) + (s0.z + s0.w)) + ((s1.x + s1.y) + (s1.z + s1.w))
              + ((s2.x + s2.y) + (s2.z + s2.w)) + ((s3.x + s3.y) + (s3.z + s3.w));
    float rinv = rden[b * 512 + t0 + lane];      // coalesced
    out[b * 512 + t0 + lane] = fmaf(num, rinv, pb);
}

// ---------------------------------------------------------------------------
extern "C" void kernel_launch(void* const* d_in, const int* in_sizes, int n_in,
                              void* d_out, int out_size, void* d_ws, size_t ws_size,
                              hipStream_t stream)
{
    (void)in_sizes; (void)n_in; (void)out_size; (void)ws_size;
    const int*   q_ids         = (const int*)d_in[0];
    const int*   responses     = (const int*)d_in[1];
    const float* q_table       = (const float*)d_in[2];
    const float* key_embeds    = (const float*)d_in[3];
    const float* alpha_mean    = (const float*)d_in[4];
    const float* alpha_log_var = (const float*)d_in[5];
    const float* beta_base     = (const float*)d_in[6];
    const float* beta_offsets  = (const float*)d_in[7];
    const float* th0           = (const float*)d_in[8];
    const float* lv0           = (const float*)d_in[9];
    const float* q2k_w         = (const float*)d_in[10];
    const float* q2k_b         = (const float*)d_in[11];
    const float* qa_w          = (const float*)d_in[12];
    const float* qa_b          = (const float*)d_in[13];
    const float* qae_w         = (const float*)d_in[14];
    const float* qae_b         = (const float*)d_in[15];
    const float* pred_w        = (const float*)d_in[16];
    const float* pred_bs       = (const float*)d_in[17];
    const float* alpha_noise   = (const float*)d_in[18];
    const float* beta_noise    = (const float*)d_in[19];
    float* ws  = (float*)d_ws;
    float* out = (float*)d_out;

    k_pre0<<<dim3(165), dim3(256), 0, stream>>>(
        q_ids, responses, key_embeds, q2k_w, q2k_b,
        alpha_mean, alpha_log_var, beta_base, beta_offsets,
        alpha_noise, beta_noise, qa_w, qa_b, qae_w, qae_b,
        pred_w, th0, lv0, ws);
    k_prep<<<dim3(626), dim3(256), 0, stream>>>(q_table, ws);
    k_reduce<<<dim3(1024), dim3(512), 0, stream>>>(ws);
    k_scan<<<dim3(64), dim3(64), 0, stream>>>(ws);
    k_pred<<<dim3(1024), dim3(512), 0, stream>>>(q_ids, pred_bs, ws, out);
}